// Round 7
// baseline (2775.710 us; speedup 1.0000x reference)
//
#include <hip/hip_runtime.h>

// LSTM_RNN: B=8192, T=2048, H=51, 2-layer LSTM + linear head.
// R11: merged homogeneous waves. R7's ~30% issue idle = L1/L2 wave imbalance
// (380 vs 540 cyc/step at a shared barrier) + duplicated h1 reads. R10 showed
// heterogeneous 2-waves/SIMD makes it worse. Here ONE wave class does BOTH
// layers for its 13-col slice each iter: read h1(k-1) frags once (shared as
// L1 A-operand and L2 p-operand), read h2(k-2), 8 L1-MFMA + 16 L2-MFMA,
// act1 -> write h1(k) (acc1 drained during L2 MFMA issue), y(k-2) from the
// gate-3 pad col, act2 -> write h2(k-1), ONE barrier. All waves identical ->
// no imbalance idle; no cross-iter acc ping-pong; y(T-1) drains at iter T+1
// (stale-h1 read is harmless: ylane's B2i is zero except bias slot).
// Block 256 thr / 4 waves, grid 512 = 2 blocks/CU; __launch_bounds__(256,2)
// caps regs at 256 (est. ~200 incl. 96 weight VGPRs -> no spill; watch
// FETCH_SIZE). Math identical to R7: packed-f32 acts, fused i*g pair-rcp,
// batch-4 Montgomery f-rcp, pre-scaled cell (-2L*c), fused sigma(o)*tanh(c),
// fp16 MFMA, x/bias K-slots 51/52, ROWW=72.

#define B_TOT 8192
#define T_LEN 2048
#define MR    16
#define ROWW  72            // f16 per row: [h 0..50][x 51][1.0 52][0 ..63][pad]
#define HB    (MR*ROWW)     // 1152 f16 per parity buffer

typedef _Float16 f16x8 __attribute__((ext_vector_type(8)));
typedef float    f32x4 __attribute__((ext_vector_type(4)));
typedef float    f32x2 __attribute__((ext_vector_type(2)));

#define LOG2E 1.4426950408889634f

static __device__ __forceinline__ float us2f(unsigned short u) {
    unsigned int w = ((unsigned int)u) << 16;
    float f; __builtin_memcpy(&f, &w, 4);
    return f;
}
// load f32 from f32 or bf16 global
static __device__ __forceinline__ float ldf(const void* p, int idx, bool isbf) {
    return isbf ? us2f(((const unsigned short*)p)[idx])
                : ((const float*)p)[idx];
}
static __device__ __forceinline__ void store_y(void* outp, bool isbf, int idx, float v) {
    if (isbf) {
        unsigned int u; __builtin_memcpy(&u, &v, 4);
        u = (u + 0x7FFFu + ((u >> 16) & 1u)) >> 16;
        ((unsigned short*)outp)[idx] = (unsigned short)u;
    } else {
        ((float*)outp)[idx] = v;
    }
}

// Packed LSTM activation + cell/h update (identical math to R7).
// acc[n][r]: n=0 i (-L*z), n=1 f (-L*z), n=2 g (-2L*z), n=3 o (-L*z).
// C[p] = cell state rows {2p,2p+1}, pre-scaled by -2L. h[p] out.
template<bool CLAMP_G>
static __device__ __forceinline__ void lstm_act(const f32x4* acc, f32x2* C, f32x2* h) {
    f32x2 di[2], df[2], dg[2], dox[2];
    #pragma unroll
    for (int p = 0; p < 2; ++p) {
        f32x2 ei, ef, eg, eo;
        #pragma unroll
        for (int e = 0; e < 2; ++e) {
            const int r = 2*p + e;
            ei[e] = __builtin_amdgcn_exp2f(acc[0][r]);
            ef[e] = __builtin_amdgcn_exp2f(acc[1][r]);
            float ag = acc[2][r];
            if (CLAMP_G) ag = __builtin_amdgcn_fmed3f(ag, -30.0f, 30.0f);
            eg[e] = __builtin_amdgcn_exp2f(ag);
            eo[e] = __builtin_amdgcn_exp2f(acc[3][r]);
        }
        di[p]  = ei + 1.0f;
        df[p]  = ef + 1.0f;
        dg[p]  = eg + 1.0f;
        dox[p] = eo + 1.0f;
    }
    f32x2 q[2], sig[2];
    q[0] = di[0]*dg[0];
    q[1] = di[1]*dg[1];
    const float Ri0 = __builtin_amdgcn_rcpf(q[0].x*q[0].y);
    const float Ri1 = __builtin_amdgcn_rcpf(q[1].x*q[1].y);
    sig[0] = (dg[0]*(2.0f*LOG2E) + (-4.0f*LOG2E)) * (q[0].yx * Ri0);
    sig[1] = (dg[1]*(2.0f*LOG2E) + (-4.0f*LOG2E)) * (q[1].yx * Ri1);
    const float pf01 = df[0].x*df[0].y;
    const float pf23 = df[1].x*df[1].y;
    const float Rf   = __builtin_amdgcn_rcpf(pf01*pf23);
    const f32x2 sf0 = df[0].yx * (Rf*pf23);
    const f32x2 sf1 = df[1].yx * (Rf*pf01);
    f32x2 tt[2], m[2];
    {
        const f32x2 Cn = sf0*C[0] + sig[0];
        C[0] = Cn;
        f32x2 e2;
        e2.x = __builtin_amdgcn_exp2f(__builtin_amdgcn_fmed3f(Cn.x, -30.0f, 30.0f));
        e2.y = __builtin_amdgcn_exp2f(__builtin_amdgcn_fmed3f(Cn.y, -30.0f, 30.0f));
        tt[0] = e2 + 1.0f;
        m[0]  = dox[0]*tt[0];
    }
    {
        const f32x2 Cn = sf1*C[1] + sig[1];
        C[1] = Cn;
        f32x2 e2;
        e2.x = __builtin_amdgcn_exp2f(__builtin_amdgcn_fmed3f(Cn.x, -30.0f, 30.0f));
        e2.y = __builtin_amdgcn_exp2f(__builtin_amdgcn_fmed3f(Cn.y, -30.0f, 30.0f));
        tt[1] = e2 + 1.0f;
        m[1]  = dox[1]*tt[1];
    }
    const float Rc = __builtin_amdgcn_rcpf(m[0].x*m[0].y);
    const float Rd = __builtin_amdgcn_rcpf(m[1].x*m[1].y);
    h[0] = (2.0f - tt[0]) * (m[0].yx * Rc);
    h[1] = (2.0f - tt[1]) * (m[1].yx * Rd);
}

__global__ __launch_bounds__(256, 2)
void lstm2_kernel(const void* __restrict__ xin,
                  const void* __restrict__ Wih1, const void* __restrict__ Whh1,
                  const void* __restrict__ bih1, const void* __restrict__ bhh1,
                  const void* __restrict__ Wih2, const void* __restrict__ Whh2,
                  const void* __restrict__ bih2, const void* __restrict__ bhh2,
                  const void* __restrict__ Wlin, const void* __restrict__ blin,
                  void* __restrict__ outp)
{
    const int tid  = threadIdx.x;
    const int wv   = tid >> 6;         // 0..3, all waves identical role
    const int ln   = tid & 63;
    const int lid  = ln & 15;
    const int quad = ln >> 4;
    const int b0   = blockIdx.x * MR;
    const int jcol = 13*wv + lid;
    const bool valid = (lid < 13) && (jcol < 51);
    const bool ylane = (wv == 3) && (lid == 12);   // pad col 51 -> y head

    __shared__ alignas(16) _Float16 hx [2*HB];   // h1 ping-pong + x/1.0 K-slots
    __shared__ alignas(16) _Float16 h2b[2*HB];   // h2 ping-pong

    // ---- dtype sniff (f32 vs bf16 globals), block-uniform ----
    bool isbf;
    {
        const unsigned short* xu = (const unsigned short*)xin;
        int cnt = 0;
        #pragma unroll
        for (int i = 0; i < 64; i += 2) {
            unsigned e = (xu[i] >> 7) & 0xFFu;
            cnt += (e >= 115u && e <= 131u) ? 1 : 0;
        }
        isbf = (cnt >= 16);
    }

    // ---- init LDS ----
    for (int i = tid; i < 2*HB; i += 256) {
        hx[i]  = (_Float16)0.0f;
        h2b[i] = (_Float16)0.0f;
    }
    __syncthreads();
    if (tid < MR) {
        hx[0*HB + tid*ROWW + 52] = (_Float16)1.0f;   // bias slot, both parities
        hx[1*HB + tid*ROWW + 52] = (_Float16)1.0f;
        hx[1*HB + tid*ROWW + 51] = (_Float16)ldf(xin, (b0 + tid)*T_LEN, isbf);
    }
    __syncthreads();

    // ---- weights: every wave holds L1 + L2 B-fragments for its col-slice ----
    f16x8 B1[4][2], B2i[4][2], B2h[4][2];
    #pragma unroll
    for (int n = 0; n < 4; ++n) {
        const int g = 51*n + jcol;
        const float sn = (n == 2) ? -2.0f*LOG2E : -LOG2E;
        #pragma unroll
        for (int kb = 0; kb < 2; ++kb) {
            f16x8 f1, fi, fh;
            #pragma unroll
            for (int j8 = 0; j8 < 8; ++j8) {
                const int k = kb*32 + quad*8 + j8;
                float v1 = 0.0f, vi = 0.0f, vh = 0.0f;
                if (valid) {
                    if (k < 51) {
                        v1 = sn * ldf(Whh1, g*51 + k, isbf);
                        vi = sn * ldf(Wih2, g*51 + k, isbf);
                        vh = sn * ldf(Whh2, g*51 + k, isbf);
                    } else if (k == 51) {
                        v1 = sn * ldf(Wih1, g, isbf);
                    } else if (k == 52) {
                        v1 = sn * (ldf(bih1, g, isbf) + ldf(bhh1, g, isbf));
                        vi = sn * (ldf(bih2, g, isbf) + ldf(bhh2, g, isbf));
                    }
                } else if (ylane && n == 3) {
                    if (k < 51)       vh = ldf(Wlin, k, isbf);
                    else if (k == 52) vi = ldf(blin, 0, isbf);
                }
                f1[j8] = (_Float16)v1; fi[j8] = (_Float16)vi; fh[j8] = (_Float16)vh;
            }
            B1[n][kb] = f1; B2i[n][kb] = fi; B2h[n][kb] = fh;
        }
    }
    f32x2 c1[2] = {{0.0f, 0.0f}, {0.0f, 0.0f}};
    f32x2 c2[2] = {{0.0f, 0.0f}, {0.0f, 0.0f}};

    // iter k: L1 computes h1(k) [k<T]; L2 computes h2(k-1) [1<=k<=T];
    // y(k-2) stored from acc2 pad col [2<=k<=T+1]. One barrier per iter.
    #pragma unroll 2
    for (int k = 0; k <= T_LEN + 1; ++k) {
        const int rs1 = (k - 1) & 1, ws1 = k & 1;       // h1 read/write parity
        const int rs2 = k & 1,       ws2 = (k - 1) & 1; // h2 read/write parity
        const bool run1 = (k < T_LEN);
        const bool mf2  = (k >= 1);
        const bool act2on = (k >= 1) && (k <= T_LEN);
        const bool xl = run1 && (tid < MR) && (k + 1 < T_LEN);
        float xnext = 0.0f;
        if (xl) xnext = ldf(xin, (b0 + tid)*T_LEN + k + 1, isbf);

        // h1(k-1) fragments: shared by L1 (A) and L2 (p-operand)
        const _Float16* h1p = &hx [rs1*HB + lid*ROWW + quad*8];
        const _Float16* h2p = &h2b[rs2*HB + lid*ROWW + quad*8];
        const f16x8 a0 = *(const f16x8*)(h1p);
        const f16x8 a1 = *(const f16x8*)(h1p + 32);
        const f16x8 q0 = *(const f16x8*)(h2p);
        const f16x8 q1 = *(const f16x8*)(h2p + 32);

        f32x4 acc1[4], acc2[4];
        __builtin_amdgcn_s_setprio(1);
        if (run1) {
            #pragma unroll
            for (int n = 0; n < 4; ++n) {
                f32x4 z = {0.0f, 0.0f, 0.0f, 0.0f};
                z       = __builtin_amdgcn_mfma_f32_16x16x32_f16(a0, B1[n][0], z, 0,0,0);
                acc1[n] = __builtin_amdgcn_mfma_f32_16x16x32_f16(a1, B1[n][1], z, 0,0,0);
            }
        }
        if (mf2) {
            #pragma unroll
            for (int n = 0; n < 4; ++n) {
                f32x4 z = {0.0f, 0.0f, 0.0f, 0.0f};
                z       = __builtin_amdgcn_mfma_f32_16x16x32_f16(a0, B2i[n][0], z, 0,0,0);
                z       = __builtin_amdgcn_mfma_f32_16x16x32_f16(a1, B2i[n][1], z, 0,0,0);
                z       = __builtin_amdgcn_mfma_f32_16x16x32_f16(q0, B2h[n][0], z, 0,0,0);
                acc2[n] = __builtin_amdgcn_mfma_f32_16x16x32_f16(q1, B2h[n][1], z, 0,0,0);
            }
        }
        __builtin_amdgcn_s_setprio(0);

        if (run1) {
            // acc1 completed while the 16 L2 MFMAs were issuing
            f32x2 h1o[2];
            lstm_act<false>(acc1, c1, h1o);
            if (valid) {
                _Float16* hw = &hx[ws1*HB + (quad*4)*ROWW + jcol];
                hw[0*ROWW] = (_Float16)h1o[0].x;
                hw[1*ROWW] = (_Float16)h1o[0].y;
                hw[2*ROWW] = (_Float16)h1o[1].x;
                hw[3*ROWW] = (_Float16)h1o[1].y;
            }
            if (xl) hx[ws1*HB + tid*ROWW + 51] = (_Float16)xnext;
        }
        if (ylane && k >= 2) {   // pad col: blin + Wlin.h2(k-2) = y[k-2]
            #pragma unroll
            for (int r = 0; r < 4; ++r)
                store_y(outp, isbf, (b0 + quad*4 + r)*T_LEN + (k - 2), acc2[3][r]);
        }
        if (act2on) {
            f32x2 h2o[2];
            lstm_act<true>(acc2, c2, h2o);
            if (valid) {
                _Float16* hw = &h2b[ws2*HB + (quad*4)*ROWW + jcol];
                hw[0*ROWW] = (_Float16)h2o[0].x;
                hw[1*ROWW] = (_Float16)h2o[0].y;
                hw[2*ROWW] = (_Float16)h2o[1].x;
                hw[3*ROWW] = (_Float16)h2o[1].y;
            }
        }
        __syncthreads();
    }
}

extern "C" void kernel_launch(void* const* d_in, const int* in_sizes, int n_in,
                              void* d_out, int out_size, void* d_ws, size_t ws_size,
                              hipStream_t stream) {
    (void)in_sizes; (void)n_in; (void)out_size; (void)d_ws; (void)ws_size;
    dim3 grid(B_TOT / MR), block(256);
    lstm2_kernel<<<grid, block, 0, stream>>>(
        d_in[0], d_in[1], d_in[2], d_in[3], d_in[4], d_in[5],
        d_in[6], d_in[7], d_in[8], d_in[9], d_in[10], d_out);
}

// Round 8
// 2352.705 us; speedup vs baseline: 1.1798x; 1.1798x over previous
//
#include <hip/hip_runtime.h>

// LSTM_RNN: B=8192, T=2048, H=51, 2-layer LSTM + linear head.
// R12 = R7 (best: 2319us) + co-resident-block anti-phasing. R7 counters are
// issue-saturated with ZERO pipe overlap (VALU 70 + MFMA 29 = 99): the
// per-step barrier phase-locks all waves AND the 2 blocks/CU phase-lock to
// each other (shared-port coupling), so MFMA and VALU windows serialize.
// m114 shows MFMA-phase and VALU-phase waves co-run at full rate. Fix: delay
// blocks >=256 (the CU-partner of block c is c+256 under 8-XCD round-robin)
// by ~half a step (s_sleep(21) ~= 1344 cyc) + a small periodic kick
// (s_sleep(3) every 128 iters) so one block's act overlaps the other's MFMA
// window. No dataflow change; downside bounded ~0.1%. Everything else
// byte-identical to R7: packed-f32 activation (v_pk_*), fused i*g pair-rcp,
// batch-4 Montgomery f-rcp, pre-scaled cell state (-2L*c), fused
// sigma(o)*tanh(c), fp16 MFMA with x/bias K-slots 51/52, ROWW=72,
// producer-consumer wave split, s_setprio, 1 barrier/step.

#define B_TOT 8192
#define T_LEN 2048
#define MR    16
#define ROWW  72            // f16 per row: [h 0..50][x 51][1.0 52][0 ..63][pad]
#define HB    (MR*ROWW)     // 1152 f16 per parity buffer

typedef _Float16 f16x8 __attribute__((ext_vector_type(8)));
typedef float    f32x4 __attribute__((ext_vector_type(4)));
typedef float    f32x2 __attribute__((ext_vector_type(2)));

#define LOG2E 1.4426950408889634f

static __device__ __forceinline__ float us2f(unsigned short u) {
    unsigned int w = ((unsigned int)u) << 16;
    float f; __builtin_memcpy(&f, &w, 4);
    return f;
}
// load f32 from f32 or bf16 global
static __device__ __forceinline__ float ldf(const void* p, int idx, bool isbf) {
    return isbf ? us2f(((const unsigned short*)p)[idx])
                : ((const float*)p)[idx];
}
static __device__ __forceinline__ void store_y(void* outp, bool isbf, int idx, float v) {
    if (isbf) {
        unsigned int u; __builtin_memcpy(&u, &v, 4);
        u = (u + 0x7FFFu + ((u >> 16) & 1u)) >> 16;
        ((unsigned short*)outp)[idx] = (unsigned short)u;
    } else {
        ((float*)outp)[idx] = v;
    }
}

// Packed LSTM activation + cell/h update (identical math to R7).
// acc[n][r]: n=0 i (-L*z), n=1 f (-L*z), n=2 g (-2L*z), n=3 o (-L*z).
// C[p] = cell state rows {2p,2p+1}, pre-scaled by -2L. h[p] out.
template<bool CLAMP_G>
static __device__ __forceinline__ void lstm_act(const f32x4* acc, f32x2* C, f32x2* h) {
    f32x2 di[2], df[2], dg[2], dox[2];
    #pragma unroll
    for (int p = 0; p < 2; ++p) {
        f32x2 ei, ef, eg, eo;
        #pragma unroll
        for (int e = 0; e < 2; ++e) {
            const int r = 2*p + e;
            ei[e] = __builtin_amdgcn_exp2f(acc[0][r]);
            ef[e] = __builtin_amdgcn_exp2f(acc[1][r]);
            float ag = acc[2][r];
            if (CLAMP_G) ag = __builtin_amdgcn_fmed3f(ag, -30.0f, 30.0f);
            eg[e] = __builtin_amdgcn_exp2f(ag);
            eo[e] = __builtin_amdgcn_exp2f(acc[3][r]);
        }
        di[p]  = ei + 1.0f;
        df[p]  = ef + 1.0f;
        dg[p]  = eg + 1.0f;
        dox[p] = eo + 1.0f;
    }
    f32x2 q[2], sig[2];
    q[0] = di[0]*dg[0];
    q[1] = di[1]*dg[1];
    const float Ri0 = __builtin_amdgcn_rcpf(q[0].x*q[0].y);
    const float Ri1 = __builtin_amdgcn_rcpf(q[1].x*q[1].y);
    sig[0] = (dg[0]*(2.0f*LOG2E) + (-4.0f*LOG2E)) * (q[0].yx * Ri0);
    sig[1] = (dg[1]*(2.0f*LOG2E) + (-4.0f*LOG2E)) * (q[1].yx * Ri1);
    const float pf01 = df[0].x*df[0].y;
    const float pf23 = df[1].x*df[1].y;
    const float Rf   = __builtin_amdgcn_rcpf(pf01*pf23);
    const f32x2 sf0 = df[0].yx * (Rf*pf23);
    const f32x2 sf1 = df[1].yx * (Rf*pf01);
    f32x2 tt[2], m[2];
    {
        const f32x2 Cn = sf0*C[0] + sig[0];
        C[0] = Cn;
        f32x2 e2;
        e2.x = __builtin_amdgcn_exp2f(__builtin_amdgcn_fmed3f(Cn.x, -30.0f, 30.0f));
        e2.y = __builtin_amdgcn_exp2f(__builtin_amdgcn_fmed3f(Cn.y, -30.0f, 30.0f));
        tt[0] = e2 + 1.0f;
        m[0]  = dox[0]*tt[0];
    }
    {
        const f32x2 Cn = sf1*C[1] + sig[1];
        C[1] = Cn;
        f32x2 e2;
        e2.x = __builtin_amdgcn_exp2f(__builtin_amdgcn_fmed3f(Cn.x, -30.0f, 30.0f));
        e2.y = __builtin_amdgcn_exp2f(__builtin_amdgcn_fmed3f(Cn.y, -30.0f, 30.0f));
        tt[1] = e2 + 1.0f;
        m[1]  = dox[1]*tt[1];
    }
    const float Rc = __builtin_amdgcn_rcpf(m[0].x*m[0].y);
    const float Rd = __builtin_amdgcn_rcpf(m[1].x*m[1].y);
    h[0] = (2.0f - tt[0]) * (m[0].yx * Rc);
    h[1] = (2.0f - tt[1]) * (m[1].yx * Rd);
}

__global__ __launch_bounds__(512, 4)
void lstm2_kernel(const void* __restrict__ xin,
                  const void* __restrict__ Wih1, const void* __restrict__ Whh1,
                  const void* __restrict__ bih1, const void* __restrict__ bhh1,
                  const void* __restrict__ Wih2, const void* __restrict__ Whh2,
                  const void* __restrict__ bih2, const void* __restrict__ bhh2,
                  const void* __restrict__ Wlin, const void* __restrict__ blin,
                  void* __restrict__ outp)
{
    const int tid  = threadIdx.x;
    const int wset = tid >> 8;         // 0: layer-1 waves, 1: layer-2 waves
    const int wv   = (tid >> 6) & 3;   // j-slice within set
    const int ln   = tid & 63;
    const int lid  = ln & 15;
    const int quad = ln >> 4;
    const int b0   = blockIdx.x * MR;
    const int jcol = 13*wv + lid;
    const bool valid = (lid < 13) && (jcol < 51);
    const bool ylane = (wv == 3) && (lid == 12);   // pad col 51 -> y head
    // CU-partner anti-phase: with grid 512 on 256 CUs (8-XCD round-robin),
    // blocks c and c+256 share a CU. Delay the upper half ~half a step.
    const bool lag = (blockIdx.x >> 8) & 1;

    __shared__ alignas(16) _Float16 hx [2*HB];   // h1 ping-pong + x/1.0 K-slots
    __shared__ alignas(16) _Float16 h2b[2*HB];   // h2 ping-pong

    // ---- dtype sniff (f32 vs bf16 globals), block-uniform ----
    bool isbf;
    {
        const unsigned short* xu = (const unsigned short*)xin;
        int cnt = 0;
        #pragma unroll
        for (int i = 0; i < 64; i += 2) {
            unsigned e = (xu[i] >> 7) & 0xFFu;
            cnt += (e >= 115u && e <= 131u) ? 1 : 0;
        }
        isbf = (cnt >= 16);
    }

    // ---- init LDS ----
    for (int i = tid; i < 2*HB; i += 512) {
        hx[i]  = (_Float16)0.0f;
        h2b[i] = (_Float16)0.0f;
    }
    __syncthreads();
    if (tid < MR) {
        hx[0*HB + tid*ROWW + 52] = (_Float16)1.0f;   // bias slot, both parities
        hx[1*HB + tid*ROWW + 52] = (_Float16)1.0f;
        hx[1*HB + tid*ROWW + 51] = (_Float16)ldf(xin, (b0 + tid)*T_LEN, isbf);
    }
    __syncthreads();

    // half-step phase offset for the CU-partner block (~1344 cyc)
    if (lag) __builtin_amdgcn_s_sleep(21);

    if (wset == 0) {
        // ================= LAYER-1 WAVES =================
        f16x8 B1[4][2];
        #pragma unroll
        for (int n = 0; n < 4; ++n) {
            const int g = 51*n + jcol;
            const float sn = (n == 2) ? -2.0f*LOG2E : -LOG2E;
            #pragma unroll
            for (int kb = 0; kb < 2; ++kb) {
                f16x8 f;
                #pragma unroll
                for (int j8 = 0; j8 < 8; ++j8) {
                    const int k = kb*32 + quad*8 + j8;
                    float v = 0.0f;
                    if (valid) {
                        if (k < 51)       v = sn * ldf(Whh1, g*51 + k, isbf);
                        else if (k == 51) v = sn * ldf(Wih1, g, isbf);
                        else if (k == 52) v = sn * (ldf(bih1, g, isbf) + ldf(bhh1, g, isbf));
                    }
                    f[j8] = (_Float16)v;
                }
                B1[n][kb] = f;
            }
        }
        f32x2 c1[2] = {{0.0f, 0.0f}, {0.0f, 0.0f}};   // pre-scaled cell (-2L*c)

        #pragma unroll 2
        for (int k = 0; k <= T_LEN; ++k) {
            if (lag && ((k & 127) == 1)) __builtin_amdgcn_s_sleep(3);  // kick
            if (k < T_LEN) {
                const int rs = (k - 1) & 1, ws = k & 1;
                // early x(k+1) prefetch (wave 0 lanes 0..15)
                const bool xl = (tid < MR) && (k + 1 < T_LEN);
                float xnext = 0.0f;
                if (xl) xnext = ldf(xin, (b0 + tid)*T_LEN + k + 1, isbf);

                const _Float16* hp = &hx[rs*HB + lid*ROWW + quad*8];
                const f16x8 a0 = *(const f16x8*)(hp);
                const f16x8 a1 = *(const f16x8*)(hp + 32);
                f32x4 acc[4];
                __builtin_amdgcn_s_setprio(1);
                #pragma unroll
                for (int n = 0; n < 4; ++n) {
                    f32x4 z = {0.0f, 0.0f, 0.0f, 0.0f};
                    z      = __builtin_amdgcn_mfma_f32_16x16x32_f16(a0, B1[n][0], z, 0,0,0);
                    acc[n] = __builtin_amdgcn_mfma_f32_16x16x32_f16(a1, B1[n][1], z, 0,0,0);
                }
                __builtin_amdgcn_s_setprio(0);
                f32x2 h[2];
                lstm_act<false>(acc, c1, h);
                if (valid) {
                    _Float16* hw = &hx[ws*HB + (quad*4)*ROWW + jcol];
                    hw[0*ROWW] = (_Float16)h[0].x;
                    hw[1*ROWW] = (_Float16)h[0].y;
                    hw[2*ROWW] = (_Float16)h[1].x;
                    hw[3*ROWW] = (_Float16)h[1].y;
                }
                if (xl) hx[ws*HB + tid*ROWW + 51] = (_Float16)xnext;
            }
            __syncthreads();
        }
    } else {
        // ================= LAYER-2 WAVES =================
        f16x8 B2i[4][2], B2h[4][2];
        #pragma unroll
        for (int n = 0; n < 4; ++n) {
            const int g = 51*n + jcol;
            const float sn = (n == 2) ? -2.0f*LOG2E : -LOG2E;
            #pragma unroll
            for (int kb = 0; kb < 2; ++kb) {
                f16x8 fi, fh;
                #pragma unroll
                for (int j8 = 0; j8 < 8; ++j8) {
                    const int k = kb*32 + quad*8 + j8;
                    float vi = 0.0f, vh = 0.0f;
                    if (valid) {
                        if (k < 51) {
                            vi = sn * ldf(Wih2, g*51 + k, isbf);
                            vh = sn * ldf(Whh2, g*51 + k, isbf);
                        } else if (k == 52) {
                            vi = sn * (ldf(bih2, g, isbf) + ldf(bhh2, g, isbf));
                        }
                    } else if (ylane && n == 3) {
                        if (k < 51)       vh = ldf(Wlin, k, isbf);
                        else if (k == 52) vi = ldf(blin, 0, isbf);
                    }
                    fi[j8] = (_Float16)vi; fh[j8] = (_Float16)vh;
                }
                B2i[n][kb] = fi; B2h[n][kb] = fh;
            }
        }
        const float bl = ldf(blin, 0, isbf);
        f32x2 c2[2] = {{0.0f, 0.0f}, {0.0f, 0.0f}};   // pre-scaled cell (-2L*c)

        #pragma unroll 2
        for (int k = 0; k <= T_LEN; ++k) {
            if (lag && ((k & 127) == 1)) __builtin_amdgcn_s_sleep(3);  // kick
            if (k >= 1) {
                const int rs1 = (k - 1) & 1;   // h1(k-1) + x/bias slots
                const int rs2 = k & 1;         // h2(k-2)
                const int ws2 = (k - 1) & 1;   // h2(k-1)
                const _Float16* h1p = &hx [rs1*HB + lid*ROWW + quad*8];
                const _Float16* h2p = &h2b[rs2*HB + lid*ROWW + quad*8];
                const f16x8 p0 = *(const f16x8*)(h1p);
                const f16x8 p1 = *(const f16x8*)(h1p + 32);
                const f16x8 q0 = *(const f16x8*)(h2p);
                const f16x8 q1 = *(const f16x8*)(h2p + 32);
                f32x4 acc[4];
                __builtin_amdgcn_s_setprio(1);
                #pragma unroll
                for (int n = 0; n < 4; ++n) {
                    f32x4 z = {0.0f, 0.0f, 0.0f, 0.0f};
                    z      = __builtin_amdgcn_mfma_f32_16x16x32_f16(p0, B2i[n][0], z, 0,0,0);
                    z      = __builtin_amdgcn_mfma_f32_16x16x32_f16(p1, B2i[n][1], z, 0,0,0);
                    z      = __builtin_amdgcn_mfma_f32_16x16x32_f16(q0, B2h[n][0], z, 0,0,0);
                    acc[n] = __builtin_amdgcn_mfma_f32_16x16x32_f16(q1, B2h[n][1], z, 0,0,0);
                }
                __builtin_amdgcn_s_setprio(0);
                if (ylane && k >= 2) {   // pad col: blin + Wlin.h2(k-2) = y[k-2]
                    #pragma unroll
                    for (int r = 0; r < 4; ++r)
                        store_y(outp, isbf, (b0 + quad*4 + r)*T_LEN + (k - 2), acc[3][r]);
                }
                f32x2 h[2];
                lstm_act<true>(acc, c2, h);
                if (valid) {
                    _Float16* hw = &h2b[ws2*HB + (quad*4)*ROWW + jcol];
                    hw[0*ROWW] = (_Float16)h[0].x;
                    hw[1*ROWW] = (_Float16)h[0].y;
                    hw[2*ROWW] = (_Float16)h[1].x;
                    hw[3*ROWW] = (_Float16)h[1].y;
                }
            }
            __syncthreads();
        }

        // ---- flush y[T-1] from final h2 (parity (T-1)&1) ----
        if (wv == 3) {
            const _Float16* h2p = &h2b[((T_LEN - 1) & 1)*HB + lid*ROWW + quad*8];
            const f16x8 q0 = *(const f16x8*)(h2p);
            const f16x8 q1 = *(const f16x8*)(h2p + 32);
            f32x4 z = {bl, bl, bl, bl};
            z = __builtin_amdgcn_mfma_f32_16x16x32_f16(q0, B2h[3][0], z, 0,0,0);
            z = __builtin_amdgcn_mfma_f32_16x16x32_f16(q1, B2h[3][1], z, 0,0,0);
            if (lid == 12) {
                #pragma unroll
                for (int r = 0; r < 4; ++r)
                    store_y(outp, isbf, (b0 + quad*4 + r)*T_LEN + (T_LEN - 1), z[r]);
            }
        }
    }
}

extern "C" void kernel_launch(void* const* d_in, const int* in_sizes, int n_in,
                              void* d_out, int out_size, void* d_ws, size_t ws_size,
                              hipStream_t stream) {
    (void)in_sizes; (void)n_in; (void)out_size; (void)d_ws; (void)ws_size;
    dim3 grid(B_TOT / MR), block(512);
    lstm2_kernel<<<grid, block, 0, stream>>>(
        d_in[0], d_in[1], d_in[2], d_in[3], d_in[4], d_in[5],
        d_in[6], d_in[7], d_in[8], d_in[9], d_in[10], d_out);
}

// Round 9
// 2306.651 us; speedup vs baseline: 1.2034x; 1.0200x over previous
//
#include <hip/hip_runtime.h>

// LSTM_RNN: B=8192, T=2048, H=51, 2-layer LSTM + linear head.
// R13 = R7 restored (best: 2319us) minus R12's sleeps (null, cost 1.4%),
// plus one free trim: the x(k+1) LDS write is hoisted ABOVE the activation
// so the pre-barrier lgkmcnt tail ends on the h-writes, not the x-write.
// Session state: 4 structural rounds (split-phase, dual-tile ILP x2, merged
// waves, anti-phase) all null-to-negative; occupancy is VGPR-capped at
// 4 waves/SIMD (L2 waves ~116 unified regs); 1 barrier/step is minimal for
// the cross-wave recurrence; MFMA count is K/N-minimal for this
// factorization; trans count is at the 5-exp/element floor. Remaining
// headroom is intra-step latency under barrier lockstep -- no remaining
// lever >3% identified. Math as R7: packed-f32 activation (v_pk_*), fused
// i*g pair-rcp, batch-4 Montgomery f-rcp, pre-scaled cell state (-2L*c),
// fused sigma(o)*tanh(c), fp16 MFMA with x/bias K-slots 51/52, ROWW=72,
// producer-consumer wave split, s_setprio, 1 barrier/step.

#define B_TOT 8192
#define T_LEN 2048
#define MR    16
#define ROWW  72            // f16 per row: [h 0..50][x 51][1.0 52][0 ..63][pad]
#define HB    (MR*ROWW)     // 1152 f16 per parity buffer

typedef _Float16 f16x8 __attribute__((ext_vector_type(8)));
typedef float    f32x4 __attribute__((ext_vector_type(4)));
typedef float    f32x2 __attribute__((ext_vector_type(2)));

#define LOG2E 1.4426950408889634f

static __device__ __forceinline__ float us2f(unsigned short u) {
    unsigned int w = ((unsigned int)u) << 16;
    float f; __builtin_memcpy(&f, &w, 4);
    return f;
}
// load f32 from f32 or bf16 global
static __device__ __forceinline__ float ldf(const void* p, int idx, bool isbf) {
    return isbf ? us2f(((const unsigned short*)p)[idx])
                : ((const float*)p)[idx];
}
static __device__ __forceinline__ void store_y(void* outp, bool isbf, int idx, float v) {
    if (isbf) {
        unsigned int u; __builtin_memcpy(&u, &v, 4);
        u = (u + 0x7FFFu + ((u >> 16) & 1u)) >> 16;
        ((unsigned short*)outp)[idx] = (unsigned short)u;
    } else {
        ((float*)outp)[idx] = v;
    }
}

// Packed LSTM activation + cell/h update (identical math to R7).
// acc[n][r]: n=0 i (-L*z), n=1 f (-L*z), n=2 g (-2L*z), n=3 o (-L*z).
// C[p] = cell state rows {2p,2p+1}, pre-scaled by -2L. h[p] out.
template<bool CLAMP_G>
static __device__ __forceinline__ void lstm_act(const f32x4* acc, f32x2* C, f32x2* h) {
    f32x2 di[2], df[2], dg[2], dox[2];
    #pragma unroll
    for (int p = 0; p < 2; ++p) {
        f32x2 ei, ef, eg, eo;
        #pragma unroll
        for (int e = 0; e < 2; ++e) {
            const int r = 2*p + e;
            ei[e] = __builtin_amdgcn_exp2f(acc[0][r]);
            ef[e] = __builtin_amdgcn_exp2f(acc[1][r]);
            float ag = acc[2][r];
            if (CLAMP_G) ag = __builtin_amdgcn_fmed3f(ag, -30.0f, 30.0f);
            eg[e] = __builtin_amdgcn_exp2f(ag);
            eo[e] = __builtin_amdgcn_exp2f(acc[3][r]);
        }
        di[p]  = ei + 1.0f;
        df[p]  = ef + 1.0f;
        dg[p]  = eg + 1.0f;
        dox[p] = eo + 1.0f;
    }
    f32x2 q[2], sig[2];
    q[0] = di[0]*dg[0];
    q[1] = di[1]*dg[1];
    const float Ri0 = __builtin_amdgcn_rcpf(q[0].x*q[0].y);
    const float Ri1 = __builtin_amdgcn_rcpf(q[1].x*q[1].y);
    sig[0] = (dg[0]*(2.0f*LOG2E) + (-4.0f*LOG2E)) * (q[0].yx * Ri0);
    sig[1] = (dg[1]*(2.0f*LOG2E) + (-4.0f*LOG2E)) * (q[1].yx * Ri1);
    const float pf01 = df[0].x*df[0].y;
    const float pf23 = df[1].x*df[1].y;
    const float Rf   = __builtin_amdgcn_rcpf(pf01*pf23);
    const f32x2 sf0 = df[0].yx * (Rf*pf23);
    const f32x2 sf1 = df[1].yx * (Rf*pf01);
    f32x2 tt[2], m[2];
    {
        const f32x2 Cn = sf0*C[0] + sig[0];
        C[0] = Cn;
        f32x2 e2;
        e2.x = __builtin_amdgcn_exp2f(__builtin_amdgcn_fmed3f(Cn.x, -30.0f, 30.0f));
        e2.y = __builtin_amdgcn_exp2f(__builtin_amdgcn_fmed3f(Cn.y, -30.0f, 30.0f));
        tt[0] = e2 + 1.0f;
        m[0]  = dox[0]*tt[0];
    }
    {
        const f32x2 Cn = sf1*C[1] + sig[1];
        C[1] = Cn;
        f32x2 e2;
        e2.x = __builtin_amdgcn_exp2f(__builtin_amdgcn_fmed3f(Cn.x, -30.0f, 30.0f));
        e2.y = __builtin_amdgcn_exp2f(__builtin_amdgcn_fmed3f(Cn.y, -30.0f, 30.0f));
        tt[1] = e2 + 1.0f;
        m[1]  = dox[1]*tt[1];
    }
    const float Rc = __builtin_amdgcn_rcpf(m[0].x*m[0].y);
    const float Rd = __builtin_amdgcn_rcpf(m[1].x*m[1].y);
    h[0] = (2.0f - tt[0]) * (m[0].yx * Rc);
    h[1] = (2.0f - tt[1]) * (m[1].yx * Rd);
}

__global__ __launch_bounds__(512, 4)
void lstm2_kernel(const void* __restrict__ xin,
                  const void* __restrict__ Wih1, const void* __restrict__ Whh1,
                  const void* __restrict__ bih1, const void* __restrict__ bhh1,
                  const void* __restrict__ Wih2, const void* __restrict__ Whh2,
                  const void* __restrict__ bih2, const void* __restrict__ bhh2,
                  const void* __restrict__ Wlin, const void* __restrict__ blin,
                  void* __restrict__ outp)
{
    const int tid  = threadIdx.x;
    const int wset = tid >> 8;         // 0: layer-1 waves, 1: layer-2 waves
    const int wv   = (tid >> 6) & 3;   // j-slice within set
    const int ln   = tid & 63;
    const int lid  = ln & 15;
    const int quad = ln >> 4;
    const int b0   = blockIdx.x * MR;
    const int jcol = 13*wv + lid;
    const bool valid = (lid < 13) && (jcol < 51);
    const bool ylane = (wv == 3) && (lid == 12);   // pad col 51 -> y head

    __shared__ alignas(16) _Float16 hx [2*HB];   // h1 ping-pong + x/1.0 K-slots
    __shared__ alignas(16) _Float16 h2b[2*HB];   // h2 ping-pong

    // ---- dtype sniff (f32 vs bf16 globals), block-uniform ----
    bool isbf;
    {
        const unsigned short* xu = (const unsigned short*)xin;
        int cnt = 0;
        #pragma unroll
        for (int i = 0; i < 64; i += 2) {
            unsigned e = (xu[i] >> 7) & 0xFFu;
            cnt += (e >= 115u && e <= 131u) ? 1 : 0;
        }
        isbf = (cnt >= 16);
    }

    // ---- init LDS ----
    for (int i = tid; i < 2*HB; i += 512) {
        hx[i]  = (_Float16)0.0f;
        h2b[i] = (_Float16)0.0f;
    }
    __syncthreads();
    if (tid < MR) {
        hx[0*HB + tid*ROWW + 52] = (_Float16)1.0f;   // bias slot, both parities
        hx[1*HB + tid*ROWW + 52] = (_Float16)1.0f;
        hx[1*HB + tid*ROWW + 51] = (_Float16)ldf(xin, (b0 + tid)*T_LEN, isbf);
    }
    __syncthreads();

    if (wset == 0) {
        // ================= LAYER-1 WAVES =================
        f16x8 B1[4][2];
        #pragma unroll
        for (int n = 0; n < 4; ++n) {
            const int g = 51*n + jcol;
            const float sn = (n == 2) ? -2.0f*LOG2E : -LOG2E;
            #pragma unroll
            for (int kb = 0; kb < 2; ++kb) {
                f16x8 f;
                #pragma unroll
                for (int j8 = 0; j8 < 8; ++j8) {
                    const int k = kb*32 + quad*8 + j8;
                    float v = 0.0f;
                    if (valid) {
                        if (k < 51)       v = sn * ldf(Whh1, g*51 + k, isbf);
                        else if (k == 51) v = sn * ldf(Wih1, g, isbf);
                        else if (k == 52) v = sn * (ldf(bih1, g, isbf) + ldf(bhh1, g, isbf));
                    }
                    f[j8] = (_Float16)v;
                }
                B1[n][kb] = f;
            }
        }
        f32x2 c1[2] = {{0.0f, 0.0f}, {0.0f, 0.0f}};   // pre-scaled cell (-2L*c)

        #pragma unroll 2
        for (int k = 0; k <= T_LEN; ++k) {
            if (k < T_LEN) {
                const int rs = (k - 1) & 1, ws = k & 1;
                // early x(k+1) prefetch (wave 0 lanes 0..15)
                const bool xl = (tid < MR) && (k + 1 < T_LEN);
                float xnext = 0.0f;
                if (xl) xnext = ldf(xin, (b0 + tid)*T_LEN + k + 1, isbf);

                const _Float16* hp = &hx[rs*HB + lid*ROWW + quad*8];
                const f16x8 a0 = *(const f16x8*)(hp);
                const f16x8 a1 = *(const f16x8*)(hp + 32);
                f32x4 acc[4];
                __builtin_amdgcn_s_setprio(1);
                #pragma unroll
                for (int n = 0; n < 4; ++n) {
                    f32x4 z = {0.0f, 0.0f, 0.0f, 0.0f};
                    z      = __builtin_amdgcn_mfma_f32_16x16x32_f16(a0, B1[n][0], z, 0,0,0);
                    acc[n] = __builtin_amdgcn_mfma_f32_16x16x32_f16(a1, B1[n][1], z, 0,0,0);
                }
                __builtin_amdgcn_s_setprio(0);
                // x-write hoisted above act: its LDS latency drains under the
                // activation instead of extending the pre-barrier tail.
                if (xl) hx[ws*HB + tid*ROWW + 51] = (_Float16)xnext;
                f32x2 h[2];
                lstm_act<false>(acc, c1, h);
                if (valid) {
                    _Float16* hw = &hx[ws*HB + (quad*4)*ROWW + jcol];
                    hw[0*ROWW] = (_Float16)h[0].x;
                    hw[1*ROWW] = (_Float16)h[0].y;
                    hw[2*ROWW] = (_Float16)h[1].x;
                    hw[3*ROWW] = (_Float16)h[1].y;
                }
            }
            __syncthreads();
        }
    } else {
        // ================= LAYER-2 WAVES =================
        f16x8 B2i[4][2], B2h[4][2];
        #pragma unroll
        for (int n = 0; n < 4; ++n) {
            const int g = 51*n + jcol;
            const float sn = (n == 2) ? -2.0f*LOG2E : -LOG2E;
            #pragma unroll
            for (int kb = 0; kb < 2; ++kb) {
                f16x8 fi, fh;
                #pragma unroll
                for (int j8 = 0; j8 < 8; ++j8) {
                    const int k = kb*32 + quad*8 + j8;
                    float vi = 0.0f, vh = 0.0f;
                    if (valid) {
                        if (k < 51) {
                            vi = sn * ldf(Wih2, g*51 + k, isbf);
                            vh = sn * ldf(Whh2, g*51 + k, isbf);
                        } else if (k == 52) {
                            vi = sn * (ldf(bih2, g, isbf) + ldf(bhh2, g, isbf));
                        }
                    } else if (ylane && n == 3) {
                        if (k < 51)       vh = ldf(Wlin, k, isbf);
                        else if (k == 52) vi = ldf(blin, 0, isbf);
                    }
                    fi[j8] = (_Float16)vi; fh[j8] = (_Float16)vh;
                }
                B2i[n][kb] = fi; B2h[n][kb] = fh;
            }
        }
        const float bl = ldf(blin, 0, isbf);
        f32x2 c2[2] = {{0.0f, 0.0f}, {0.0f, 0.0f}};   // pre-scaled cell (-2L*c)

        #pragma unroll 2
        for (int k = 0; k <= T_LEN; ++k) {
            if (k >= 1) {
                const int rs1 = (k - 1) & 1;   // h1(k-1) + x/bias slots
                const int rs2 = k & 1;         // h2(k-2)
                const int ws2 = (k - 1) & 1;   // h2(k-1)
                const _Float16* h1p = &hx [rs1*HB + lid*ROWW + quad*8];
                const _Float16* h2p = &h2b[rs2*HB + lid*ROWW + quad*8];
                const f16x8 p0 = *(const f16x8*)(h1p);
                const f16x8 p1 = *(const f16x8*)(h1p + 32);
                const f16x8 q0 = *(const f16x8*)(h2p);
                const f16x8 q1 = *(const f16x8*)(h2p + 32);
                f32x4 acc[4];
                __builtin_amdgcn_s_setprio(1);
                #pragma unroll
                for (int n = 0; n < 4; ++n) {
                    f32x4 z = {0.0f, 0.0f, 0.0f, 0.0f};
                    z      = __builtin_amdgcn_mfma_f32_16x16x32_f16(p0, B2i[n][0], z, 0,0,0);
                    z      = __builtin_amdgcn_mfma_f32_16x16x32_f16(p1, B2i[n][1], z, 0,0,0);
                    z      = __builtin_amdgcn_mfma_f32_16x16x32_f16(q0, B2h[n][0], z, 0,0,0);
                    acc[n] = __builtin_amdgcn_mfma_f32_16x16x32_f16(q1, B2h[n][1], z, 0,0,0);
                }
                __builtin_amdgcn_s_setprio(0);
                if (ylane && k >= 2) {   // pad col: blin + Wlin.h2(k-2) = y[k-2]
                    #pragma unroll
                    for (int r = 0; r < 4; ++r)
                        store_y(outp, isbf, (b0 + quad*4 + r)*T_LEN + (k - 2), acc[3][r]);
                }
                f32x2 h[2];
                lstm_act<true>(acc, c2, h);
                if (valid) {
                    _Float16* hw = &h2b[ws2*HB + (quad*4)*ROWW + jcol];
                    hw[0*ROWW] = (_Float16)h[0].x;
                    hw[1*ROWW] = (_Float16)h[0].y;
                    hw[2*ROWW] = (_Float16)h[1].x;
                    hw[3*ROWW] = (_Float16)h[1].y;
                }
            }
            __syncthreads();
        }

        // ---- flush y[T-1] from final h2 (parity (T-1)&1) ----
        if (wv == 3) {
            const _Float16* h2p = &h2b[((T_LEN - 1) & 1)*HB + lid*ROWW + quad*8];
            const f16x8 q0 = *(const f16x8*)(h2p);
            const f16x8 q1 = *(const f16x8*)(h2p + 32);
            f32x4 z = {bl, bl, bl, bl};
            z = __builtin_amdgcn_mfma_f32_16x16x32_f16(q0, B2h[3][0], z, 0,0,0);
            z = __builtin_amdgcn_mfma_f32_16x16x32_f16(q1, B2h[3][1], z, 0,0,0);
            if (lid == 12) {
                #pragma unroll
                for (int r = 0; r < 4; ++r)
                    store_y(outp, isbf, (b0 + quad*4 + r)*T_LEN + (T_LEN - 1), z[r]);
            }
        }
    }
}

extern "C" void kernel_launch(void* const* d_in, const int* in_sizes, int n_in,
                              void* d_out, int out_size, void* d_ws, size_t ws_size,
                              hipStream_t stream) {
    (void)in_sizes; (void)n_in; (void)out_size; (void)d_ws; (void)ws_size;
    dim3 grid(B_TOT / MR), block(512);
    lstm2_kernel<<<grid, block, 0, stream>>>(
        d_in[0], d_in[1], d_in[2], d_in[3], d_in[4], d_in[5],
        d_in[6], d_in[7], d_in[8], d_in[9], d_in[10], d_out);
}